// Round 8
// baseline (380.001 us; speedup 1.0000x reference)
//
#include <hip/hip_runtime.h>
#include <hip/hip_bf16.h>

// Problem constants
#define NB    4
#define NP    12          // P1 == P == 12
#define NN_   207
#define DM    128         // d_model
#define DHID  256
#define M_TOK 9936        // NB*NP*NN_
#define MPH   9984        // padded rows (78*128)

typedef float        f32x4 __attribute__((ext_vector_type(4)));
typedef unsigned int u32x4 __attribute__((ext_vector_type(4)));
typedef __bf16       bf16x8 __attribute__((ext_vector_type(8)));

static __device__ __forceinline__ unsigned int pk_bf2(float a, float b) {
    __hip_bfloat16 ba = __float2bfloat16(a);
    __hip_bfloat16 bb = __float2bfloat16(b);
    unsigned short ua = *reinterpret_cast<unsigned short*>(&ba);
    unsigned short ub = *reinterpret_cast<unsigned short*>(&bb);
    return (unsigned int)ua | ((unsigned int)ub << 16);
}
static __device__ __forceinline__ float dot4(f32x4 a, f32x4 b) {
    return a[0] * b[0] + a[1] * b[1] + a[2] * b[2] + a[3] * b[3];
}

// ---------------- prep: W2->bf16 | meta (h->bf16, Qb) ----------------
// blocks [0,2048): cvt_w2; [2048,2204): meta, 64 tokens each, weights in VGPRs
__global__ __launch_bounds__(256) void k_prep(const float* __restrict__ W2,
                                              unsigned short* __restrict__ W2b,
                                              const float* __restrict__ x,
                                              const float* __restrict__ ct,
                                              const float* __restrict__ W1,
                                              const float* __restrict__ b1,
                                              const float* __restrict__ b2,
                                              unsigned short* __restrict__ hbf,
                                              float* __restrict__ Qb) {
    const int t = threadIdx.x;
    const int bid = blockIdx.x;
    if (bid < 2048) {
        int i = bid * 256 + t;
        const f32x4* in = reinterpret_cast<const f32x4*>(W2);
        f32x4 v0 = in[2 * i], v1 = in[2 * i + 1];
        u32x4 o;
        o[0] = pk_bf2(v0[0], v0[1]);
        o[1] = pk_bf2(v0[2], v0[3]);
        o[2] = pk_bf2(v1[0], v1[1]);
        o[3] = pk_bf2(v1[2], v1[3]);
        reinterpret_cast<u32x4*>(W2b)[i] = o;
        return;
    }
    const int m0 = (bid - 2048) * 64;
    {   // h: thread t owns hidden unit j=t; W1 row in 128 VGPRs; ct rows broadcast
        const f32x4* w1r = reinterpret_cast<const f32x4*>(&W1[(size_t)t * DM]);
        f32x4 wreg[32];
        #pragma unroll
        for (int c = 0; c < 32; ++c) wreg[c] = w1r[c];
        const float bb = b1[t];
        for (int tok = 0; tok < 64; ++tok) {
            int m = m0 + tok;
            if (m >= M_TOK) break;
            const f32x4* cr = reinterpret_cast<const f32x4*>(&ct[(size_t)m * DM]);
            float acc = 0.0f;
            #pragma unroll
            for (int c = 0; c < 32; ++c) acc += dot4(wreg[c], cr[c]);
            float hv = fmaxf(acc + bb, 0.0f);
            __hip_bfloat16 hb = __float2bfloat16(hv);
            hbf[(size_t)m * DHID + t] = *reinterpret_cast<unsigned short*>(&hb);
        }
    }
    {   // Qb: thread owns o=t&127, token-half t>>7; b2 row in 128 VGPRs
        const int o  = t & 127;
        const int th = (t >> 7) * 32;
        const f32x4* b2r = reinterpret_cast<const f32x4*>(&b2[(size_t)o * DM]);
        f32x4 wreg[32];
        #pragma unroll
        for (int c = 0; c < 32; ++c) wreg[c] = b2r[c];
        for (int tok = 0; tok < 32; ++tok) {
            int m = m0 + th + tok;
            if (m >= M_TOK) break;
            const f32x4* xr = reinterpret_cast<const f32x4*>(&x[(size_t)m * DM]);
            float acc = 0.0f;
            #pragma unroll
            for (int c = 0; c < 32; ++c) acc += dot4(wreg[c], xr[c]);
            Qb[(size_t)m * DM + o] = acc;
        }
    }
}

// ---------------- G-form GEMM: G[od,m] = sum_j W2b[od,j]*hbf[m,j]; then ----------------
// QpT[o][m] = sum_d xin[m,d]*G[o*128+d, m]  (block od-range = one o, all 128 d)
// Block 128od x 128m, BK=32 (8 steps), dbuf LDS, XOR chunk swizzle, 4 waves of 128od x 32m.
// bid = mb*128 + odb -> XCD = odb%8 -> per-XCD W2b working set 1MB (L2-resident).
__global__ __launch_bounds__(256, 3) void k_gemm(const unsigned short* __restrict__ W2b,
                                                 const unsigned short* __restrict__ hbf,
                                                 const float* __restrict__ xin,
                                                 float* __restrict__ QpT) {
    __shared__ unsigned short As[2][4096];   // [128 rows][32 j], 64B rows
    __shared__ unsigned short Bs[2][4096];
    const int t = threadIdx.x;
    const int odb = blockIdx.x & 127;
    const int mb  = blockIdx.x >> 7;         // 0..77
    const int od0 = odb * 128;
    const int m0  = mb * 128;
    const int w = t >> 6;
    const int l = t & 63;
    const int lr = l & 15;
    const int g  = l >> 4;

    // staging: thread covers local rows srow, srow+16; global j-chunk l&3; swizzled LDS chunk
    const int srow  = w * 32 + (l >> 2);
    const int swz   = ((l & 3) ^ ((l >> 2) & 3)) * 8;
    const int wOff0 = srow * 32 + swz;
    const int wOff1 = (srow + 16) * 32 + swz;
    const unsigned short* aS0 = W2b + (size_t)(od0 + srow) * 256 + (l & 3) * 8;
    const unsigned short* aS1 = aS0 + 16 * 256;
    const unsigned short* bS0 = hbf + (size_t)(m0 + srow) * 256 + (l & 3) * 8;
    const unsigned short* bS1 = bS0 + 16 * 256;

    // read offsets (swizzle: LDS chunk = g ^ (row&3))
    const int aR = lr * 32 + ((g ^ (lr & 3)) * 8);             // + fo*512
    const int bR = (w * 32 + lr) * 32 + ((g ^ (lr & 3)) * 8);  // + fm*512

    f32x4 acc[8][2];
    #pragma unroll
    for (int fo = 0; fo < 8; ++fo) {
        acc[fo][0] = (f32x4)(0.0f);
        acc[fo][1] = (f32x4)(0.0f);
    }

    // prologue: stage step 0, prefetch step 1
    {
        u32x4 cA0 = *reinterpret_cast<const u32x4*>(aS0);
        u32x4 cA1 = *reinterpret_cast<const u32x4*>(aS1);
        u32x4 cB0 = *reinterpret_cast<const u32x4*>(bS0);
        u32x4 cB1 = *reinterpret_cast<const u32x4*>(bS1);
        *reinterpret_cast<u32x4*>(&As[0][wOff0]) = cA0;
        *reinterpret_cast<u32x4*>(&As[0][wOff1]) = cA1;
        *reinterpret_cast<u32x4*>(&Bs[0][wOff0]) = cB0;
        *reinterpret_cast<u32x4*>(&Bs[0][wOff1]) = cB1;
    }
    u32x4 nA0 = *reinterpret_cast<const u32x4*>(aS0 + 32);
    u32x4 nA1 = *reinterpret_cast<const u32x4*>(aS1 + 32);
    u32x4 nB0 = *reinterpret_cast<const u32x4*>(bS0 + 32);
    u32x4 nB1 = *reinterpret_cast<const u32x4*>(bS1 + 32);
    __syncthreads();

    int cur = 0;
    #pragma unroll
    for (int s = 0; s < 8; ++s) {
        bf16x8 bf0 = *reinterpret_cast<const bf16x8*>(&Bs[cur][bR]);
        bf16x8 bf1 = *reinterpret_cast<const bf16x8*>(&Bs[cur][bR + 512]);
        if (s < 7) {      // write prefetched step s+1 into other buffer
            *reinterpret_cast<u32x4*>(&As[cur ^ 1][wOff0]) = nA0;
            *reinterpret_cast<u32x4*>(&As[cur ^ 1][wOff1]) = nA1;
            *reinterpret_cast<u32x4*>(&Bs[cur ^ 1][wOff0]) = nB0;
            *reinterpret_cast<u32x4*>(&Bs[cur ^ 1][wOff1]) = nB1;
        }
        if (s < 6) {      // prefetch step s+2 from global (j advances 32/step)
            nA0 = *reinterpret_cast<const u32x4*>(aS0 + (s + 2) * 32);
            nA1 = *reinterpret_cast<const u32x4*>(aS1 + (s + 2) * 32);
            nB0 = *reinterpret_cast<const u32x4*>(bS0 + (s + 2) * 32);
            nB1 = *reinterpret_cast<const u32x4*>(bS1 + (s + 2) * 32);
        }
        __builtin_amdgcn_s_setprio(1);
        #pragma unroll
        for (int fo = 0; fo < 8; ++fo) {
            bf16x8 af = *reinterpret_cast<const bf16x8*>(&As[cur][fo * 512 + aR]);
            acc[fo][0] = __builtin_amdgcn_mfma_f32_16x16x32_bf16(af, bf0, acc[fo][0], 0, 0, 0);
            acc[fo][1] = __builtin_amdgcn_mfma_f32_16x16x32_bf16(af, bf1, acc[fo][1], 0, 0, 0);
        }
        __builtin_amdgcn_s_setprio(0);
        __syncthreads();
        cur ^= 1;
    }

    // epilogue: acc[fo][fm][r] = G[od0 + fo*16 + g*4 + r][m0 + w*32 + fm*16 + lr]
    // d-local = fo*16+g*4+r; contract with x, reduce over g-groups, write QpT[odb][m]
    const int m0w = m0 + w * 32;
    #pragma unroll
    for (int fm = 0; fm < 2; ++fm) {
        int m = m0w + fm * 16 + lr;
        int mx = m < M_TOK ? m : (M_TOK - 1);
        const f32x4* xr = reinterpret_cast<const f32x4*>(&xin[(size_t)mx * DM]);
        float q = 0.0f;
        #pragma unroll
        for (int fo = 0; fo < 8; ++fo) {
            f32x4 xv = xr[fo * 4 + g];
            q += xv[0] * acc[fo][fm][0] + xv[1] * acc[fo][fm][1]
               + xv[2] * acc[fo][fm][2] + xv[3] * acc[fo][fm][3];
        }
        q += __shfl_xor(q, 16, 64);
        q += __shfl_xor(q, 32, 64);
        if (l < 16 && m < M_TOK) QpT[(size_t)odb * MPH + m] = q;
    }
}

// ---------------- attention + W_out(global-stream) + residual + layernorm ----------------
__global__ __launch_bounds__(256) void k_attn(const float* __restrict__ QpT,
                                              const float* __restrict__ Qb,
                                              const float* __restrict__ Kenc,
                                              const float* __restrict__ Venc,
                                              const float* __restrict__ xin,
                                              const float* __restrict__ Wout,
                                              const float* __restrict__ gamma,
                                              const float* __restrict__ beta,
                                              float* __restrict__ out) {
    __shared__ float Qs[12][132];
    __shared__ float Ks[12][132];
    __shared__ float Vs[12][132];
    __shared__ float Ss[12][12][8];
    __shared__ float Os[12][132];
    const int t = threadIdx.x;
    const int b = blockIdx.x / NN_;
    const int n = blockIdx.x % NN_;

    // Q = Qb + QpT (transpose-gather, 5MB L2/L3-hot)
    for (int e = t; e < 1536; e += 256) {
        int row = e >> 7, o = e & 127;
        size_t mrow = (size_t)(b * NP + row) * NN_ + n;
        Qs[row][o] = Qb[mrow * DM + o] + QpT[(size_t)o * MPH + mrow];
    }
    for (int e = t; e < 384; e += 256) {
        int row = e >> 5, c4 = e & 31;
        size_t mrow = (size_t)(b * NP + row) * NN_ + n;
        *reinterpret_cast<f32x4*>(&Ks[row][c4 * 4]) =
            *reinterpret_cast<const f32x4*>(&Kenc[mrow * DM + c4 * 4]);
        *reinterpret_cast<f32x4*>(&Vs[row][c4 * 4]) =
            *reinterpret_cast<const f32x4*>(&Venc[mrow * DM + c4 * 4]);
    }
    __syncthreads();
    if (t < 144) {
        int q = t / 12, p = t % 12;
        #pragma unroll
        for (int hh = 0; hh < 8; ++hh) {
            const f32x4* qv = reinterpret_cast<const f32x4*>(&Qs[q][hh * 16]);
            const f32x4* kv = reinterpret_cast<const f32x4*>(&Ks[p][hh * 16]);
            float s = 0.0f;
            #pragma unroll
            for (int c = 0; c < 4; ++c) {
                f32x4 a = qv[c], bb = kv[c];
                s += a[0] * bb[0] + a[1] * bb[1] + a[2] * bb[2] + a[3] * bb[3];
            }
            Ss[q][p][hh] = s * 0.25f;
        }
    }
    __syncthreads();
    if (t < 96) {
        int q = t >> 3, hh = t & 7;
        float mx = -1e30f;
        #pragma unroll
        for (int p = 0; p < 12; ++p) mx = fmaxf(mx, Ss[q][p][hh]);
        float ev[12]; float sum = 0.0f;
        #pragma unroll
        for (int p = 0; p < 12; ++p) { ev[p] = __expf(Ss[q][p][hh] - mx); sum += ev[p]; }
        float inv = 1.0f / sum;
        #pragma unroll
        for (int p = 0; p < 12; ++p) Ss[q][p][hh] = ev[p] * inv;
    }
    __syncthreads();
    #pragma unroll
    for (int i = 0; i < 6; ++i) {
        int e = i * 256 + t;
        int q = e >> 7, hk = e & 127, hh = hk >> 4;
        float acc = 0.0f;
        #pragma unroll
        for (int p = 0; p < 12; ++p) acc += Ss[q][p][hh] * Vs[p][hk];
        Os[q][hk] = acc;
    }
    __syncthreads();
    {   // projection: thread owns col o for 6 q-rows; W_out streamed from global
        const int o  = t & 127;
        const int qh = (t >> 7) * 6;
        const f32x4* wrow = reinterpret_cast<const f32x4*>(&Wout[(size_t)o * DM]);
        float pacc[6] = {0, 0, 0, 0, 0, 0};
        for (int c = 0; c < 32; ++c) {
            f32x4 wv = wrow[c];
            #pragma unroll
            for (int qq = 0; qq < 6; ++qq) {
                f32x4 ov = *reinterpret_cast<const f32x4*>(&Os[qh + qq][c * 4]);
                pacc[qq] += wv[0] * ov[0] + wv[1] * ov[1] + wv[2] * ov[2] + wv[3] * ov[3];
            }
        }
        #pragma unroll
        for (int qq = 0; qq < 6; ++qq) {
            size_t mrow = (size_t)(b * NP + qh + qq) * NN_ + n;
            Qs[qh + qq][o] = pacc[qq] + xin[mrow * DM + o];
        }
    }
    __syncthreads();
    const int wv_ = t >> 6, l = t & 63;
    for (int rq = wv_; rq < 12; rq += 4) {
        float v0 = Qs[rq][l], v1 = Qs[rq][l + 64];
        float s = v0 + v1, ss = v0 * v0 + v1 * v1;
        #pragma unroll
        for (int msk = 1; msk < 64; msk <<= 1) {
            s += __shfl_xor(s, msk, 64);
            ss += __shfl_xor(ss, msk, 64);
        }
        float mu = s * (1.0f / 128.0f);
        float var = ss * (1.0f / 128.0f) - mu * mu;
        float rs = rsqrtf(var + 1e-5f);
        size_t mrow = (size_t)(b * NP + rq) * NN_ + n;
        out[mrow * DM + l]      = (v0 - mu) * rs * gamma[l] + beta[l];
        out[mrow * DM + l + 64] = (v1 - mu) * rs * gamma[l + 64] + beta[l + 64];
    }
}

// ---------------- launcher ----------------
extern "C" void kernel_launch(void* const* d_in, const int* in_sizes, int n_in,
                              void* d_out, int out_size, void* d_ws, size_t ws_size,
                              hipStream_t stream) {
    const float* xin   = (const float*)d_in[0];
    const float* Kenc  = (const float*)d_in[1];
    const float* Venc  = (const float*)d_in[2];
    const float* ct    = (const float*)d_in[3];
    const float* W1    = (const float*)d_in[4];
    const float* b1    = (const float*)d_in[5];
    const float* W2    = (const float*)d_in[6];
    const float* b2    = (const float*)d_in[7];
    const float* Wout  = (const float*)d_in[8];
    const float* gamma = (const float*)d_in[9];
    const float* beta  = (const float*)d_in[10];
    float* out = (float*)d_out;

    char* ws = (char*)d_ws;
    unsigned short* W2b = (unsigned short*)(ws);              //  8,388,608 B  [16384][256] bf16
    unsigned short* hbf = (unsigned short*)(ws + 8388608);    //  5,111,808 B  [9984][256] bf16
    float* Qb  = (float*)(ws + 13500416);                     //  5,087,232 B  [9936][128] f32
    float* QpT = (float*)(ws + 18587648);                     //  5,111,808 B  [128][9984] f32

    // zero the hbf pad rows (9936..9983) so the GEMM's B-tail is clean
    hipMemsetAsync(ws + 8388608 + (size_t)M_TOK * DHID * 2, 0,
                   (size_t)(MPH - M_TOK) * DHID * 2, stream);
    hipLaunchKernelGGL(k_prep, dim3(2204), dim3(256), 0, stream,
                       W2, W2b, xin, ct, W1, b1, b2, hbf, Qb);
    hipLaunchKernelGGL(k_gemm, dim3(78 * 128), dim3(256), 0, stream, W2b, hbf, xin, QpT);
    hipLaunchKernelGGL(k_attn, dim3(828), dim3(256), 0, stream, QpT, Qb, Kenc, Venc,
                       xin, Wout, gamma, beta, out);
}

// Round 9
// 247.551 us; speedup vs baseline: 1.5350x; 1.5350x over previous
//
#include <hip/hip_runtime.h>
#include <hip/hip_bf16.h>

// Problem constants
#define NB    4
#define NP    12          // P1 == P == 12
#define NN_   207
#define DM    128         // d_model
#define DHID  256
#define M_TOK 9936        // NB*NP*NN_
#define MPH   9984        // padded rows (78*128)

typedef float        f32x4 __attribute__((ext_vector_type(4)));
typedef unsigned int u32x4 __attribute__((ext_vector_type(4)));
typedef __bf16       bf16x8 __attribute__((ext_vector_type(8)));

static __device__ __forceinline__ unsigned int pk_bf2(float a, float b) {
    __hip_bfloat16 ba = __float2bfloat16(a);
    __hip_bfloat16 bb = __float2bfloat16(b);
    unsigned short ua = *reinterpret_cast<unsigned short*>(&ba);
    unsigned short ub = *reinterpret_cast<unsigned short*>(&bb);
    return (unsigned int)ua | ((unsigned int)ub << 16);
}
static __device__ __forceinline__ float dot4(f32x4 a, f32x4 b) {
    return a[0] * b[0] + a[1] * b[1] + a[2] * b[2] + a[3] * b[3];
}

// ---------------- prep: W2->bf16 | meta (h->bf16, Qb) ----------------
// blocks [0,2048): cvt_w2; [2048,2359): meta, 32 tokens each, ct/x staged in LDS,
// weights STREAMED from global (L2-hot) — NOT register-cached (r8 spilled to scratch).
__global__ __launch_bounds__(256) void k_prep(const float* __restrict__ W2,
                                              unsigned short* __restrict__ W2b,
                                              const float* __restrict__ x,
                                              const float* __restrict__ ct,
                                              const float* __restrict__ W1,
                                              const float* __restrict__ b1,
                                              const float* __restrict__ b2,
                                              unsigned short* __restrict__ hbf,
                                              float* __restrict__ Qb) {
    const int t = threadIdx.x;
    const int bid = blockIdx.x;
    if (bid < 2048) {
        int i = bid * 256 + t;
        const f32x4* in = reinterpret_cast<const f32x4*>(W2);
        f32x4 v0 = in[2 * i], v1 = in[2 * i + 1];
        u32x4 o;
        o[0] = pk_bf2(v0[0], v0[1]);
        o[1] = pk_bf2(v0[2], v0[3]);
        o[2] = pk_bf2(v1[0], v1[1]);
        o[3] = pk_bf2(v1[2], v1[3]);
        reinterpret_cast<u32x4*>(W2b)[i] = o;
        return;
    }
    __shared__ float cts[32][128];
    __shared__ float xs[32][128];
    const int m0 = (bid - 2048) * 32;
    // stage 32 tokens of ct and x (1024 f32x4 each)
    for (int e = t; e < 1024; e += 256) {
        int tok = e >> 5, c4 = e & 31;
        int m = m0 + tok;
        f32x4 cv = (f32x4)(0.0f), xv = (f32x4)(0.0f);
        if (m < M_TOK) {
            cv = *reinterpret_cast<const f32x4*>(&ct[(size_t)m * DM + c4 * 4]);
            xv = *reinterpret_cast<const f32x4*>(&x[(size_t)m * DM + c4 * 4]);
        }
        *reinterpret_cast<f32x4*>(&cts[tok][c4 * 4]) = cv;
        *reinterpret_cast<f32x4*>(&xs[tok][c4 * 4]) = xv;
    }
    __syncthreads();
    {   // h: thread t owns hidden unit j = t for 32 tokens; W1 row streamed
        const int j = t;
        const f32x4* w1r = reinterpret_cast<const f32x4*>(&W1[(size_t)j * DM]);
        float acc[32];
        #pragma unroll
        for (int tok = 0; tok < 32; ++tok) acc[tok] = 0.0f;
        for (int c = 0; c < 32; ++c) {
            f32x4 wv = w1r[c];
            #pragma unroll
            for (int tok = 0; tok < 32; ++tok)
                acc[tok] += dot4(wv, *reinterpret_cast<const f32x4*>(&cts[tok][c * 4]));
        }
        const float bb = b1[j];
        #pragma unroll
        for (int tok = 0; tok < 32; ++tok) {
            int m = m0 + tok;
            if (m < M_TOK) {
                float hv = fmaxf(acc[tok] + bb, 0.0f);
                __hip_bfloat16 hb = __float2bfloat16(hv);
                hbf[(size_t)m * DHID + j] = *reinterpret_cast<unsigned short*>(&hb);
            }
        }
    }
    {   // Qb: thread owns o = t&127, token-half (t>>7)*16; b2 row streamed
        const int o  = t & 127;
        const int th = (t >> 7) * 16;
        const f32x4* b2r = reinterpret_cast<const f32x4*>(&b2[(size_t)o * DM]);
        float acc[16];
        #pragma unroll
        for (int tt = 0; tt < 16; ++tt) acc[tt] = 0.0f;
        for (int c = 0; c < 32; ++c) {
            f32x4 wv = b2r[c];
            #pragma unroll
            for (int tt = 0; tt < 16; ++tt)
                acc[tt] += dot4(wv, *reinterpret_cast<const f32x4*>(&xs[th + tt][c * 4]));
        }
        #pragma unroll
        for (int tt = 0; tt < 16; ++tt) {
            int m = m0 + th + tt;
            if (m < M_TOK) Qb[(size_t)m * DM + o] = acc[tt];
        }
    }
}

// ---------------- G-form GEMM: G[od,m] = sum_j W2b[od,j]*hbf[m,j]; then ----------------
// QpT[o][m] = sum_d xin[m,d]*G[o*128+d, m]  (block od-range = one o, all 128 d)
// Block 128od x 128m, BK=32 (8 steps), dbuf LDS, XOR chunk swizzle, 4 waves of 128od x 32m.
// bid = mb*128 + odb -> XCD = odb%8 -> per-XCD W2b working set 1MB (L2-resident).
__global__ __launch_bounds__(256, 3) void k_gemm(const unsigned short* __restrict__ W2b,
                                                 const unsigned short* __restrict__ hbf,
                                                 const float* __restrict__ xin,
                                                 float* __restrict__ QpT) {
    __shared__ unsigned short As[2][4096];   // [128 rows][32 j], 64B rows
    __shared__ unsigned short Bs[2][4096];
    const int t = threadIdx.x;
    const int odb = blockIdx.x & 127;
    const int mb  = blockIdx.x >> 7;         // 0..77
    const int od0 = odb * 128;
    const int m0  = mb * 128;
    const int w = t >> 6;
    const int l = t & 63;
    const int lr = l & 15;
    const int g  = l >> 4;

    // staging: thread covers local rows srow, srow+16; global j-chunk l&3; swizzled LDS chunk
    const int srow  = w * 32 + (l >> 2);
    const int swz   = ((l & 3) ^ ((l >> 2) & 3)) * 8;
    const int wOff0 = srow * 32 + swz;
    const int wOff1 = (srow + 16) * 32 + swz;
    const unsigned short* aS0 = W2b + (size_t)(od0 + srow) * 256 + (l & 3) * 8;
    const unsigned short* aS1 = aS0 + 16 * 256;
    const unsigned short* bS0 = hbf + (size_t)(m0 + srow) * 256 + (l & 3) * 8;
    const unsigned short* bS1 = bS0 + 16 * 256;

    // read offsets (swizzle: LDS chunk = g ^ (row&3))
    const int aR = lr * 32 + ((g ^ (lr & 3)) * 8);             // + fo*512
    const int bR = (w * 32 + lr) * 32 + ((g ^ (lr & 3)) * 8);  // + fm*512

    f32x4 acc[8][2];
    #pragma unroll
    for (int fo = 0; fo < 8; ++fo) {
        acc[fo][0] = (f32x4)(0.0f);
        acc[fo][1] = (f32x4)(0.0f);
    }

    // prologue: stage step 0, prefetch step 1
    {
        u32x4 cA0 = *reinterpret_cast<const u32x4*>(aS0);
        u32x4 cA1 = *reinterpret_cast<const u32x4*>(aS1);
        u32x4 cB0 = *reinterpret_cast<const u32x4*>(bS0);
        u32x4 cB1 = *reinterpret_cast<const u32x4*>(bS1);
        *reinterpret_cast<u32x4*>(&As[0][wOff0]) = cA0;
        *reinterpret_cast<u32x4*>(&As[0][wOff1]) = cA1;
        *reinterpret_cast<u32x4*>(&Bs[0][wOff0]) = cB0;
        *reinterpret_cast<u32x4*>(&Bs[0][wOff1]) = cB1;
    }
    u32x4 nA0 = *reinterpret_cast<const u32x4*>(aS0 + 32);
    u32x4 nA1 = *reinterpret_cast<const u32x4*>(aS1 + 32);
    u32x4 nB0 = *reinterpret_cast<const u32x4*>(bS0 + 32);
    u32x4 nB1 = *reinterpret_cast<const u32x4*>(bS1 + 32);
    __syncthreads();

    int cur = 0;
    #pragma unroll
    for (int s = 0; s < 8; ++s) {
        bf16x8 bf0 = *reinterpret_cast<const bf16x8*>(&Bs[cur][bR]);
        bf16x8 bf1 = *reinterpret_cast<const bf16x8*>(&Bs[cur][bR + 512]);
        if (s < 7) {      // write prefetched step s+1 into other buffer
            *reinterpret_cast<u32x4*>(&As[cur ^ 1][wOff0]) = nA0;
            *reinterpret_cast<u32x4*>(&As[cur ^ 1][wOff1]) = nA1;
            *reinterpret_cast<u32x4*>(&Bs[cur ^ 1][wOff0]) = nB0;
            *reinterpret_cast<u32x4*>(&Bs[cur ^ 1][wOff1]) = nB1;
        }
        if (s < 6) {      // prefetch step s+2 from global (j advances 32/step)
            nA0 = *reinterpret_cast<const u32x4*>(aS0 + (s + 2) * 32);
            nA1 = *reinterpret_cast<const u32x4*>(aS1 + (s + 2) * 32);
            nB0 = *reinterpret_cast<const u32x4*>(bS0 + (s + 2) * 32);
            nB1 = *reinterpret_cast<const u32x4*>(bS1 + (s + 2) * 32);
        }
        __builtin_amdgcn_s_setprio(1);
        #pragma unroll
        for (int fo = 0; fo < 8; ++fo) {
            bf16x8 af = *reinterpret_cast<const bf16x8*>(&As[cur][fo * 512 + aR]);
            acc[fo][0] = __builtin_amdgcn_mfma_f32_16x16x32_bf16(af, bf0, acc[fo][0], 0, 0, 0);
            acc[fo][1] = __builtin_amdgcn_mfma_f32_16x16x32_bf16(af, bf1, acc[fo][1], 0, 0, 0);
        }
        __builtin_amdgcn_s_setprio(0);
        __syncthreads();
        cur ^= 1;
    }

    // epilogue: acc[fo][fm][r] = G[od0 + fo*16 + g*4 + r][m0 + w*32 + fm*16 + lr]
    // d-local = fo*16+g*4+r; contract with x, reduce over g-groups, write QpT[odb][m]
    const int m0w = m0 + w * 32;
    #pragma unroll
    for (int fm = 0; fm < 2; ++fm) {
        int m = m0w + fm * 16 + lr;
        int mx = m < M_TOK ? m : (M_TOK - 1);
        const f32x4* xr = reinterpret_cast<const f32x4*>(&xin[(size_t)mx * DM]);
        float q = 0.0f;
        #pragma unroll
        for (int fo = 0; fo < 8; ++fo) {
            f32x4 xv = xr[fo * 4 + g];
            q += xv[0] * acc[fo][fm][0] + xv[1] * acc[fo][fm][1]
               + xv[2] * acc[fo][fm][2] + xv[3] * acc[fo][fm][3];
        }
        q += __shfl_xor(q, 16, 64);
        q += __shfl_xor(q, 32, 64);
        if (l < 16 && m < M_TOK) QpT[(size_t)odb * MPH + m] = q;
    }
}

// ---------------- attention + W_out(global-stream) + residual + layernorm ----------------
__global__ __launch_bounds__(256) void k_attn(const float* __restrict__ QpT,
                                              const float* __restrict__ Qb,
                                              const float* __restrict__ Kenc,
                                              const float* __restrict__ Venc,
                                              const float* __restrict__ xin,
                                              const float* __restrict__ Wout,
                                              const float* __restrict__ gamma,
                                              const float* __restrict__ beta,
                                              float* __restrict__ out) {
    __shared__ float Qs[12][132];
    __shared__ float Ks[12][132];
    __shared__ float Vs[12][132];
    __shared__ float Ss[12][12][8];
    __shared__ float Os[12][132];
    const int t = threadIdx.x;
    const int b = blockIdx.x / NN_;
    const int n = blockIdx.x % NN_;

    // Q = Qb + QpT (transpose-gather, 5MB L2/L3-hot)
    for (int e = t; e < 1536; e += 256) {
        int row = e >> 7, o = e & 127;
        size_t mrow = (size_t)(b * NP + row) * NN_ + n;
        Qs[row][o] = Qb[mrow * DM + o] + QpT[(size_t)o * MPH + mrow];
    }
    for (int e = t; e < 384; e += 256) {
        int row = e >> 5, c4 = e & 31;
        size_t mrow = (size_t)(b * NP + row) * NN_ + n;
        *reinterpret_cast<f32x4*>(&Ks[row][c4 * 4]) =
            *reinterpret_cast<const f32x4*>(&Kenc[mrow * DM + c4 * 4]);
        *reinterpret_cast<f32x4*>(&Vs[row][c4 * 4]) =
            *reinterpret_cast<const f32x4*>(&Venc[mrow * DM + c4 * 4]);
    }
    __syncthreads();
    if (t < 144) {
        int q = t / 12, p = t % 12;
        #pragma unroll
        for (int hh = 0; hh < 8; ++hh) {
            const f32x4* qv = reinterpret_cast<const f32x4*>(&Qs[q][hh * 16]);
            const f32x4* kv = reinterpret_cast<const f32x4*>(&Ks[p][hh * 16]);
            float s = 0.0f;
            #pragma unroll
            for (int c = 0; c < 4; ++c) {
                f32x4 a = qv[c], bb = kv[c];
                s += a[0] * bb[0] + a[1] * bb[1] + a[2] * bb[2] + a[3] * bb[3];
            }
            Ss[q][p][hh] = s * 0.25f;
        }
    }
    __syncthreads();
    if (t < 96) {
        int q = t >> 3, hh = t & 7;
        float mx = -1e30f;
        #pragma unroll
        for (int p = 0; p < 12; ++p) mx = fmaxf(mx, Ss[q][p][hh]);
        float ev[12]; float sum = 0.0f;
        #pragma unroll
        for (int p = 0; p < 12; ++p) { ev[p] = __expf(Ss[q][p][hh] - mx); sum += ev[p]; }
        float inv = 1.0f / sum;
        #pragma unroll
        for (int p = 0; p < 12; ++p) Ss[q][p][hh] = ev[p] * inv;
    }
    __syncthreads();
    #pragma unroll
    for (int i = 0; i < 6; ++i) {
        int e = i * 256 + t;
        int q = e >> 7, hk = e & 127, hh = hk >> 4;
        float acc = 0.0f;
        #pragma unroll
        for (int p = 0; p < 12; ++p) acc += Ss[q][p][hh] * Vs[p][hk];
        Os[q][hk] = acc;
    }
    __syncthreads();
    {   // projection: thread owns col o for 6 q-rows; W_out streamed from global
        const int o  = t & 127;
        const int qh = (t >> 7) * 6;
        const f32x4* wrow = reinterpret_cast<const f32x4*>(&Wout[(size_t)o * DM]);
        float pacc[6] = {0, 0, 0, 0, 0, 0};
        for (int c = 0; c < 32; ++c) {
            f32x4 wv = wrow[c];
            #pragma unroll
            for (int qq = 0; qq < 6; ++qq) {
                f32x4 ov = *reinterpret_cast<const f32x4*>(&Os[qh + qq][c * 4]);
                pacc[qq] += wv[0] * ov[0] + wv[1] * ov[1] + wv[2] * ov[2] + wv[3] * ov[3];
            }
        }
        #pragma unroll
        for (int qq = 0; qq < 6; ++qq) {
            size_t mrow = (size_t)(b * NP + qh + qq) * NN_ + n;
            Qs[qh + qq][o] = pacc[qq] + xin[mrow * DM + o];
        }
    }
    __syncthreads();
    const int wv_ = t >> 6, l = t & 63;
    for (int rq = wv_; rq < 12; rq += 4) {
        float v0 = Qs[rq][l], v1 = Qs[rq][l + 64];
        float s = v0 + v1, ss = v0 * v0 + v1 * v1;
        #pragma unroll
        for (int msk = 1; msk < 64; msk <<= 1) {
            s += __shfl_xor(s, msk, 64);
            ss += __shfl_xor(ss, msk, 64);
        }
        float mu = s * (1.0f / 128.0f);
        float var = ss * (1.0f / 128.0f) - mu * mu;
        float rs = rsqrtf(var + 1e-5f);
        size_t mrow = (size_t)(b * NP + rq) * NN_ + n;
        out[mrow * DM + l]      = (v0 - mu) * rs * gamma[l] + beta[l];
        out[mrow * DM + l + 64] = (v1 - mu) * rs * gamma[l + 64] + beta[l + 64];
    }
}

// ---------------- launcher ----------------
extern "C" void kernel_launch(void* const* d_in, const int* in_sizes, int n_in,
                              void* d_out, int out_size, void* d_ws, size_t ws_size,
                              hipStream_t stream) {
    const float* xin   = (const float*)d_in[0];
    const float* Kenc  = (const float*)d_in[1];
    const float* Venc  = (const float*)d_in[2];
    const float* ct    = (const float*)d_in[3];
    const float* W1    = (const float*)d_in[4];
    const float* b1    = (const float*)d_in[5];
    const float* W2    = (const float*)d_in[6];
    const float* b2    = (const float*)d_in[7];
    const float* Wout  = (const float*)d_in[8];
    const float* gamma = (const float*)d_in[9];
    const float* beta  = (const float*)d_in[10];
    float* out = (float*)d_out;

    char* ws = (char*)d_ws;
    unsigned short* W2b = (unsigned short*)(ws);              //  8,388,608 B  [16384][256] bf16
    unsigned short* hbf = (unsigned short*)(ws + 8388608);    //  5,111,808 B  [9984][256] bf16
    float* Qb  = (float*)(ws + 13500416);                     //  5,087,232 B  [9936][128] f32
    float* QpT = (float*)(ws + 18587648);                     //  5,111,808 B  [128][9984] f32

    // zero the hbf pad rows (9936..9983) so the GEMM's B-tail is clean
    hipMemsetAsync(ws + 8388608 + (size_t)M_TOK * DHID * 2, 0,
                   (size_t)(MPH - M_TOK) * DHID * 2, stream);
    hipLaunchKernelGGL(k_prep, dim3(2359), dim3(256), 0, stream,
                       W2, W2b, xin, ct, W1, b1, b2, hbf, Qb);
    hipLaunchKernelGGL(k_gemm, dim3(78 * 128), dim3(256), 0, stream, W2b, hbf, xin, QpT);
    hipLaunchKernelGGL(k_attn, dim3(828), dim3(256), 0, stream, QpT, Qb, Kenc, Venc,
                       xin, Wout, gamma, beta, out);
}

// Round 10
// 200.640 us; speedup vs baseline: 1.8939x; 1.2338x over previous
//
#include <hip/hip_runtime.h>
#include <hip/hip_bf16.h>

// Problem constants
#define NB    4
#define NP    12          // P1 == P == 12
#define NN_   207
#define DM    128         // d_model
#define DHID  256
#define M_TOK 9936        // NB*NP*NN_
#define MPH   9984        // padded rows (78*128)

typedef float        f32x4 __attribute__((ext_vector_type(4)));
typedef unsigned int u32x4 __attribute__((ext_vector_type(4)));
typedef __bf16       bf16x8 __attribute__((ext_vector_type(8)));

static __device__ __forceinline__ unsigned int pk_bf2(float a, float b) {
    __hip_bfloat16 ba = __float2bfloat16(a);
    __hip_bfloat16 bb = __float2bfloat16(b);
    unsigned short ua = *reinterpret_cast<unsigned short*>(&ba);
    unsigned short ub = *reinterpret_cast<unsigned short*>(&bb);
    return (unsigned int)ua | ((unsigned int)ub << 16);
}

// ---------------- prep: W2->bf16 | meta-MFMA (h->bf16, Qb) ----------------
// blocks [0,2048): cvt_w2.
// blocks [2048,2126): meta, 128 tokens each: h = relu(ct@W1^T + b1) via bf16 MFMA,
//   Qb = x@b2resh^T via bf16 MFMA. ct/x/weight-chunks staged to LDS as bf16 with
//   granule-XOR swizzle (pos = g ^ (row&7)); all global reads coalesced.
__global__ __launch_bounds__(256) void k_prep(const float* __restrict__ W2,
                                              unsigned short* __restrict__ W2b,
                                              const float* __restrict__ x,
                                              const float* __restrict__ ct,
                                              const float* __restrict__ W1,
                                              const float* __restrict__ b1,
                                              const float* __restrict__ b2,
                                              unsigned short* __restrict__ hbf,
                                              float* __restrict__ Qb) {
    const int t = threadIdx.x;
    const int bid = blockIdx.x;
    if (bid < 2048) {
        int i = bid * 256 + t;
        const f32x4* in = reinterpret_cast<const f32x4*>(W2);
        f32x4 v0 = in[2 * i], v1 = in[2 * i + 1];
        u32x4 o;
        o[0] = pk_bf2(v0[0], v0[1]);
        o[1] = pk_bf2(v0[2], v0[3]);
        o[2] = pk_bf2(v1[0], v1[1]);
        o[3] = pk_bf2(v1[2], v1[3]);
        reinterpret_cast<u32x4*>(W2b)[i] = o;
        return;
    }
    __shared__ unsigned short AB[128 * 128];   // 32KB: ct_bf then x_bf, swizzled
    __shared__ unsigned short WB[64 * 128];    // 16KB: W1b / b2b chunk, swizzled
    const int m0 = (bid - 2048) * 128;
    const int w = t >> 6, l = t & 63;
    const int lr = l & 15, g = l >> 4;

    // ---- stage ct -> AB (bf16, swizzled), coalesced 32B reads ----
    #pragma unroll
    for (int it = 0; it < 8; ++it) {
        int r = (t >> 4) + it * 16;
        int gg = t & 15;
        int m = m0 + r;
        f32x4 a = (f32x4)(0.0f), b = (f32x4)(0.0f);
        if (m < M_TOK) {
            a = *reinterpret_cast<const f32x4*>(&ct[(size_t)m * DM + gg * 8]);
            b = *reinterpret_cast<const f32x4*>(&ct[(size_t)m * DM + gg * 8 + 4]);
        }
        u32x4 pk;
        pk[0] = pk_bf2(a[0], a[1]); pk[1] = pk_bf2(a[2], a[3]);
        pk[2] = pk_bf2(b[0], b[1]); pk[3] = pk_bf2(b[2], b[3]);
        *reinterpret_cast<u32x4*>(&AB[r * 128 + ((gg ^ (r & 7)) * 8)]) = pk;
    }

    // ---- h: 4 chunks of 64 hidden units ----
    for (int jc = 0; jc < 4; ++jc) {
        __syncthreads();   // WB free (prev readers done); AB visible (first iter)
        #pragma unroll
        for (int it = 0; it < 4; ++it) {
            int r = (t >> 4) + it * 16;
            int gg = t & 15;
            const float* src = &W1[(size_t)(jc * 64 + r) * DM + gg * 8];
            f32x4 a = *reinterpret_cast<const f32x4*>(src);
            f32x4 b = *reinterpret_cast<const f32x4*>(src + 4);
            u32x4 pk;
            pk[0] = pk_bf2(a[0], a[1]); pk[1] = pk_bf2(a[2], a[3]);
            pk[2] = pk_bf2(b[0], b[1]); pk[3] = pk_bf2(b[2], b[3]);
            *reinterpret_cast<u32x4*>(&WB[r * 128 + ((gg ^ (r & 7)) * 8)]) = pk;
        }
        __syncthreads();
        f32x4 acc[2][4];
        #pragma unroll
        for (int a2 = 0; a2 < 2; ++a2)
            #pragma unroll
            for (int jf = 0; jf < 4; ++jf) acc[a2][jf] = (f32x4)(0.0f);
        #pragma unroll
        for (int ks = 0; ks < 4; ++ks) {
            bf16x8 A2[2], B4[4];
            #pragma unroll
            for (int tf = 0; tf < 2; ++tf) {
                int row = (2 * w + tf) * 16 + lr;
                A2[tf] = *reinterpret_cast<const bf16x8*>(
                    &AB[row * 128 + (((ks * 4 + g) ^ (row & 7)) * 8)]);
            }
            #pragma unroll
            for (int jf = 0; jf < 4; ++jf) {
                int row = jf * 16 + lr;
                B4[jf] = *reinterpret_cast<const bf16x8*>(
                    &WB[row * 128 + (((ks * 4 + g) ^ (row & 7)) * 8)]);
            }
            #pragma unroll
            for (int tf = 0; tf < 2; ++tf)
                #pragma unroll
                for (int jf = 0; jf < 4; ++jf)
                    acc[tf][jf] = __builtin_amdgcn_mfma_f32_16x16x32_bf16(
                        A2[tf], B4[jf], acc[tf][jf], 0, 0, 0);
        }
        // epilogue: D row = token (g*4+rr), col = j (lr)
        #pragma unroll
        for (int jf = 0; jf < 4; ++jf) {
            int j = jc * 64 + jf * 16 + lr;
            float bv = b1[j];
            #pragma unroll
            for (int tf = 0; tf < 2; ++tf)
                #pragma unroll
                for (int rr = 0; rr < 4; ++rr) {
                    int m = m0 + (2 * w + tf) * 16 + g * 4 + rr;
                    if (m < M_TOK) {
                        float hv = fmaxf(acc[tf][jf][rr] + bv, 0.0f);
                        __hip_bfloat16 hb = __float2bfloat16(hv);
                        hbf[(size_t)m * DHID + j] = *reinterpret_cast<unsigned short*>(&hb);
                    }
                }
        }
    }

    // ---- Qb: restage AB with x, 2 chunks of 64 outputs ----
    __syncthreads();   // all h-phase AB reads done
    #pragma unroll
    for (int it = 0; it < 8; ++it) {
        int r = (t >> 4) + it * 16;
        int gg = t & 15;
        int m = m0 + r;
        f32x4 a = (f32x4)(0.0f), b = (f32x4)(0.0f);
        if (m < M_TOK) {
            a = *reinterpret_cast<const f32x4*>(&x[(size_t)m * DM + gg * 8]);
            b = *reinterpret_cast<const f32x4*>(&x[(size_t)m * DM + gg * 8 + 4]);
        }
        u32x4 pk;
        pk[0] = pk_bf2(a[0], a[1]); pk[1] = pk_bf2(a[2], a[3]);
        pk[2] = pk_bf2(b[0], b[1]); pk[3] = pk_bf2(b[2], b[3]);
        *reinterpret_cast<u32x4*>(&AB[r * 128 + ((gg ^ (r & 7)) * 8)]) = pk;
    }
    for (int oc = 0; oc < 2; ++oc) {
        #pragma unroll
        for (int it = 0; it < 4; ++it) {
            int r = (t >> 4) + it * 16;
            int gg = t & 15;
            const float* src = &b2[(size_t)(oc * 64 + r) * DM + gg * 8];
            f32x4 a = *reinterpret_cast<const f32x4*>(src);
            f32x4 b = *reinterpret_cast<const f32x4*>(src + 4);
            u32x4 pk;
            pk[0] = pk_bf2(a[0], a[1]); pk[1] = pk_bf2(a[2], a[3]);
            pk[2] = pk_bf2(b[0], b[1]); pk[3] = pk_bf2(b[2], b[3]);
            *reinterpret_cast<u32x4*>(&WB[r * 128 + ((gg ^ (r & 7)) * 8)]) = pk;
        }
        __syncthreads();
        f32x4 acc[2][4];
        #pragma unroll
        for (int a2 = 0; a2 < 2; ++a2)
            #pragma unroll
            for (int of = 0; of < 4; ++of) acc[a2][of] = (f32x4)(0.0f);
        #pragma unroll
        for (int ks = 0; ks < 4; ++ks) {
            bf16x8 A2[2], B4[4];
            #pragma unroll
            for (int tf = 0; tf < 2; ++tf) {
                int row = (2 * w + tf) * 16 + lr;
                A2[tf] = *reinterpret_cast<const bf16x8*>(
                    &AB[row * 128 + (((ks * 4 + g) ^ (row & 7)) * 8)]);
            }
            #pragma unroll
            for (int of = 0; of < 4; ++of) {
                int row = of * 16 + lr;
                B4[of] = *reinterpret_cast<const bf16x8*>(
                    &WB[row * 128 + (((ks * 4 + g) ^ (row & 7)) * 8)]);
            }
            #pragma unroll
            for (int tf = 0; tf < 2; ++tf)
                #pragma unroll
                for (int of = 0; of < 4; ++of)
                    acc[tf][of] = __builtin_amdgcn_mfma_f32_16x16x32_bf16(
                        A2[tf], B4[of], acc[tf][of], 0, 0, 0);
        }
        #pragma unroll
        for (int of = 0; of < 4; ++of) {
            int o = oc * 64 + of * 16 + lr;
            #pragma unroll
            for (int tf = 0; tf < 2; ++tf)
                #pragma unroll
                for (int rr = 0; rr < 4; ++rr) {
                    int m = m0 + (2 * w + tf) * 16 + g * 4 + rr;
                    if (m < M_TOK) Qb[(size_t)m * DM + o] = acc[tf][of][rr];
                }
        }
        __syncthreads();   // before next WB overwrite
    }
}

// ---------------- G-form GEMM: G[od,m] = sum_j W2b[od,j]*hbf[m,j]; then ----------------
// QpT[o][m] = sum_d xin[m,d]*G[o*128+d, m]  (block od-range = one o, all 128 d)
// Block 128od x 128m, BK=32 (8 steps), dbuf LDS, r2-style XOR swizzle (chunk ^ (row>>1)&3
// — r9's (row&3) variant was a 4-way bank conflict, 12.8M conflicts), 4 waves 128od x 32m.
__global__ __launch_bounds__(256, 3) void k_gemm(const unsigned short* __restrict__ W2b,
                                                 const unsigned short* __restrict__ hbf,
                                                 const float* __restrict__ xin,
                                                 float* __restrict__ QpT) {
    __shared__ unsigned short As[2][4096];   // [128 rows][32 j], 64B rows
    __shared__ unsigned short Bs[2][4096];
    const int t = threadIdx.x;
    const int odb = blockIdx.x & 127;
    const int mb  = blockIdx.x >> 7;         // 0..77
    const int od0 = odb * 128;
    const int m0  = mb * 128;
    const int w = t >> 6;
    const int l = t & 63;
    const int lr = l & 15;
    const int g  = l >> 4;

    // staging: thread covers local rows srow, srow+16; global j-chunk l&3
    const int srow  = w * 32 + (l >> 2);
    const int swz   = ((l & 3) ^ ((l >> 3) & 3)) * 8;     // chunk ^ ((srow>>1)&3)
    const int wOff0 = srow * 32 + swz;
    const int wOff1 = (srow + 16) * 32 + swz;             // (srow+16)>>1 &3 unchanged
    const unsigned short* aS0 = W2b + (size_t)(od0 + srow) * 256 + (l & 3) * 8;
    const unsigned short* aS1 = aS0 + 16 * 256;
    const unsigned short* bS0 = hbf + (size_t)(m0 + srow) * 256 + (l & 3) * 8;
    const unsigned short* bS1 = bS0 + 16 * 256;

    // read offsets: chunk position = g ^ ((row>>1)&3); row = fo*16+lr or w*32+lr
    const int aR = lr * 32 + ((g ^ ((lr >> 1) & 3)) * 8);             // + fo*512
    const int bR = (w * 32 + lr) * 32 + ((g ^ ((lr >> 1) & 3)) * 8);  // + fm*512

    f32x4 acc[8][2];
    #pragma unroll
    for (int fo = 0; fo < 8; ++fo) {
        acc[fo][0] = (f32x4)(0.0f);
        acc[fo][1] = (f32x4)(0.0f);
    }

    // prologue: stage step 0, prefetch step 1
    {
        u32x4 cA0 = *reinterpret_cast<const u32x4*>(aS0);
        u32x4 cA1 = *reinterpret_cast<const u32x4*>(aS1);
        u32x4 cB0 = *reinterpret_cast<const u32x4*>(bS0);
        u32x4 cB1 = *reinterpret_cast<const u32x4*>(bS1);
        *reinterpret_cast<u32x4*>(&As[0][wOff0]) = cA0;
        *reinterpret_cast<u32x4*>(&As[0][wOff1]) = cA1;
        *reinterpret_cast<u32x4*>(&Bs[0][wOff0]) = cB0;
        *reinterpret_cast<u32x4*>(&Bs[0][wOff1]) = cB1;
    }
    u32x4 nA0 = *reinterpret_cast<const u32x4*>(aS0 + 32);
    u32x4 nA1 = *reinterpret_cast<const u32x4*>(aS1 + 32);
    u32x4 nB0 = *reinterpret_cast<const u32x4*>(bS0 + 32);
    u32x4 nB1 = *reinterpret_cast<const u32x4*>(bS1 + 32);
    __syncthreads();

    int cur = 0;
    #pragma unroll
    for (int s = 0; s < 8; ++s) {
        bf16x8 bf0 = *reinterpret_cast<const bf16x8*>(&Bs[cur][bR]);
        bf16x8 bf1 = *reinterpret_cast<const bf16x8*>(&Bs[cur][bR + 512]);
        if (s < 7) {      // write prefetched step s+1 into other buffer
            *reinterpret_cast<u32x4*>(&As[cur ^ 1][wOff0]) = nA0;
            *reinterpret_cast<u32x4*>(&As[cur ^ 1][wOff1]) = nA1;
            *reinterpret_cast<u32x4*>(&Bs[cur ^ 1][wOff0]) = nB0;
            *reinterpret_cast<u32x4*>(&Bs[cur ^ 1][wOff1]) = nB1;
        }
        if (s < 6) {      // prefetch step s+2 from global (j advances 32/step)
            nA0 = *reinterpret_cast<const u32x4*>(aS0 + (s + 2) * 32);
            nA1 = *reinterpret_cast<const u32x4*>(aS1 + (s + 2) * 32);
            nB0 = *reinterpret_cast<const u32x4*>(bS0 + (s + 2) * 32);
            nB1 = *reinterpret_cast<const u32x4*>(bS1 + (s + 2) * 32);
        }
        __builtin_amdgcn_s_setprio(1);
        #pragma unroll
        for (int fo = 0; fo < 8; ++fo) {
            bf16x8 af = *reinterpret_cast<const bf16x8*>(&As[cur][fo * 512 + aR]);
            acc[fo][0] = __builtin_amdgcn_mfma_f32_16x16x32_bf16(af, bf0, acc[fo][0], 0, 0, 0);
            acc[fo][1] = __builtin_amdgcn_mfma_f32_16x16x32_bf16(af, bf1, acc[fo][1], 0, 0, 0);
        }
        __builtin_amdgcn_s_setprio(0);
        __syncthreads();
        cur ^= 1;
    }

    // epilogue: acc[fo][fm][r] = G[od0 + fo*16 + g*4 + r][m0 + w*32 + fm*16 + lr]
    const int m0w = m0 + w * 32;
    #pragma unroll
    for (int fm = 0; fm < 2; ++fm) {
        int m = m0w + fm * 16 + lr;
        int mx = m < M_TOK ? m : (M_TOK - 1);
        const f32x4* xr = reinterpret_cast<const f32x4*>(&xin[(size_t)mx * DM]);
        float q = 0.0f;
        #pragma unroll
        for (int fo = 0; fo < 8; ++fo) {
            f32x4 xv = xr[fo * 4 + g];
            q += xv[0] * acc[fo][fm][0] + xv[1] * acc[fo][fm][1]
               + xv[2] * acc[fo][fm][2] + xv[3] * acc[fo][fm][3];
        }
        q += __shfl_xor(q, 16, 64);
        q += __shfl_xor(q, 32, 64);
        if (l < 16 && m < M_TOK) QpT[(size_t)odb * MPH + m] = q;
    }
}

// ---------------- attention + W_out(global-stream) + residual + layernorm ----------------
__global__ __launch_bounds__(256) void k_attn(const float* __restrict__ QpT,
                                              const float* __restrict__ Qb,
                                              const float* __restrict__ Kenc,
                                              const float* __restrict__ Venc,
                                              const float* __restrict__ xin,
                                              const float* __restrict__ Wout,
                                              const float* __restrict__ gamma,
                                              const float* __restrict__ beta,
                                              float* __restrict__ out) {
    __shared__ float Qs[12][132];
    __shared__ float Ks[12][132];
    __shared__ float Vs[12][132];
    __shared__ float Ss[12][12][8];
    __shared__ float Os[12][132];
    const int t = threadIdx.x;
    const int b = blockIdx.x / NN_;
    const int n = blockIdx.x % NN_;

    for (int e = t; e < 1536; e += 256) {
        int row = e >> 7, o = e & 127;
        size_t mrow = (size_t)(b * NP + row) * NN_ + n;
        Qs[row][o] = Qb[mrow * DM + o] + QpT[(size_t)o * MPH + mrow];
    }
    for (int e = t; e < 384; e += 256) {
        int row = e >> 5, c4 = e & 31;
        size_t mrow = (size_t)(b * NP + row) * NN_ + n;
        *reinterpret_cast<f32x4*>(&Ks[row][c4 * 4]) =
            *reinterpret_cast<const f32x4*>(&Kenc[mrow * DM + c4 * 4]);
        *reinterpret_cast<f32x4*>(&Vs[row][c4 * 4]) =
            *reinterpret_cast<const f32x4*>(&Venc[mrow * DM + c4 * 4]);
    }
    __syncthreads();
    if (t < 144) {
        int q = t / 12, p = t % 12;
        #pragma unroll
        for (int hh = 0; hh < 8; ++hh) {
            const f32x4* qv = reinterpret_cast<const f32x4*>(&Qs[q][hh * 16]);
            const f32x4* kv = reinterpret_cast<const f32x4*>(&Ks[p][hh * 16]);
            float s = 0.0f;
            #pragma unroll
            for (int c = 0; c < 4; ++c) {
                f32x4 a = qv[c], bb = kv[c];
                s += a[0] * bb[0] + a[1] * bb[1] + a[2] * bb[2] + a[3] * bb[3];
            }
            Ss[q][p][hh] = s * 0.25f;
        }
    }
    __syncthreads();
    if (t < 96) {
        int q = t >> 3, hh = t & 7;
        float mx = -1e30f;
        #pragma unroll
        for (int p = 0; p < 12; ++p) mx = fmaxf(mx, Ss[q][p][hh]);
        float ev[12]; float sum = 0.0f;
        #pragma unroll
        for (int p = 0; p < 12; ++p) { ev[p] = __expf(Ss[q][p][hh] - mx); sum += ev[p]; }
        float inv = 1.0f / sum;
        #pragma unroll
        for (int p = 0; p < 12; ++p) Ss[q][p][hh] = ev[p] * inv;
    }
    __syncthreads();
    #pragma unroll
    for (int i = 0; i < 6; ++i) {
        int e = i * 256 + t;
        int q = e >> 7, hk = e & 127, hh = hk >> 4;
        float acc = 0.0f;
        #pragma unroll
        for (int p = 0; p < 12; ++p) acc += Ss[q][p][hh] * Vs[p][hk];
        Os[q][hk] = acc;
    }
    __syncthreads();
    {   // projection: thread owns col o for 6 q-rows; W_out streamed from global
        const int o  = t & 127;
        const int qh = (t >> 7) * 6;
        const f32x4* wrow = reinterpret_cast<const f32x4*>(&Wout[(size_t)o * DM]);
        float pacc[6] = {0, 0, 0, 0, 0, 0};
        for (int c = 0; c < 32; ++c) {
            f32x4 wv = wrow[c];
            #pragma unroll
            for (int qq = 0; qq < 6; ++qq) {
                f32x4 ov = *reinterpret_cast<const f32x4*>(&Os[qh + qq][c * 4]);
                pacc[qq] += wv[0] * ov[0] + wv[1] * ov[1] + wv[2] * ov[2] + wv[3] * ov[3];
            }
        }
        #pragma unroll
        for (int qq = 0; qq < 6; ++qq) {
            size_t mrow = (size_t)(b * NP + qh + qq) * NN_ + n;
            Qs[qh + qq][o] = pacc[qq] + xin[mrow * DM + o];
        }
    }
    __syncthreads();
    const int wv_ = t >> 6, ll = t & 63;
    for (int rq = wv_; rq < 12; rq += 4) {
        float v0 = Qs[rq][ll], v1 = Qs[rq][ll + 64];
        float s = v0 + v1, ss = v0 * v0 + v1 * v1;
        #pragma unroll
        for (int msk = 1; msk < 64; msk <<= 1) {
            s += __shfl_xor(s, msk, 64);
            ss += __shfl_xor(ss, msk, 64);
        }
        float mu = s * (1.0f / 128.0f);
        float var = ss * (1.0f / 128.0f) - mu * mu;
        float rs = rsqrtf(var + 1e-5f);
        size_t mrow = (size_t)(b * NP + rq) * NN_ + n;
        out[mrow * DM + ll]      = (v0 - mu) * rs * gamma[ll] + beta[ll];
        out[mrow * DM + ll + 64] = (v1 - mu) * rs * gamma[ll + 64] + beta[ll + 64];
    }
}

// ---------------- launcher ----------------
extern "C" void kernel_launch(void* const* d_in, const int* in_sizes, int n_in,
                              void* d_out, int out_size, void* d_ws, size_t ws_size,
                              hipStream_t stream) {
    const float* xin   = (const float*)d_in[0];
    const float* Kenc  = (const float*)d_in[1];
    const float* Venc  = (const float*)d_in[2];
    const float* ct    = (const float*)d_in[3];
    const float* W1    = (const float*)d_in[4];
    const float* b1    = (const float*)d_in[5];
    const float* W2    = (const float*)d_in[6];
    const float* b2    = (const float*)d_in[7];
    const float* Wout  = (const float*)d_in[8];
    const float* gamma = (const float*)d_in[9];
    const float* beta  = (const float*)d_in[10];
    float* out = (float*)d_out;

    char* ws = (char*)d_ws;
    unsigned short* W2b = (unsigned short*)(ws);              //  8,388,608 B  [16384][256] bf16
    unsigned short* hbf = (unsigned short*)(ws + 8388608);    //  5,111,808 B  [9984][256] bf16
    float* Qb  = (float*)(ws + 13500416);                     //  5,087,232 B  [9936][128] f32
    float* QpT = (float*)(ws + 18587648);                     //  5,111,808 B  [128][9984] f32

    // zero the hbf pad rows (9936..9983) so the GEMM's B-tail is clean
    hipMemsetAsync(ws + 8388608 + (size_t)M_TOK * DHID * 2, 0,
                   (size_t)(MPH - M_TOK) * DHID * 2, stream);
    hipLaunchKernelGGL(k_prep, dim3(2126), dim3(256), 0, stream,
                       W2, W2b, xin, ct, W1, b1, b2, hbf, Qb);
    hipLaunchKernelGGL(k_gemm, dim3(78 * 128), dim3(256), 0, stream, W2b, hbf, xin, QpT);
    hipLaunchKernelGGL(k_attn, dim3(828), dim3(256), 0, stream, QpT, Qb, Kenc, Venc,
                       xin, Wout, gamma, beta, out);
}

// Round 11
// 196.402 us; speedup vs baseline: 1.9348x; 1.0216x over previous
//
#include <hip/hip_runtime.h>
#include <hip/hip_bf16.h>

// Problem constants
#define NB    4
#define NP    12          // P1 == P == 12
#define NN_   207
#define DM    128         // d_model
#define DHID  256
#define M_TOK 9936        // NB*NP*NN_
#define MPH   9984        // padded rows (78*128)

typedef float        f32x4 __attribute__((ext_vector_type(4)));
typedef unsigned int u32x4 __attribute__((ext_vector_type(4)));
typedef __bf16       bf16x8 __attribute__((ext_vector_type(8)));

static __device__ __forceinline__ unsigned int pk_bf2(float a, float b) {
    __hip_bfloat16 ba = __float2bfloat16(a);
    __hip_bfloat16 bb = __float2bfloat16(b);
    unsigned short ua = *reinterpret_cast<unsigned short*>(&ba);
    unsigned short ub = *reinterpret_cast<unsigned short*>(&bb);
    return (unsigned int)ua | ((unsigned int)ub << 16);
}

// ---------------- prep: W2->bf16 | meta-MFMA (h->bf16, Qb) ----------------
// (unchanged from round 10 — verified)
__global__ __launch_bounds__(256) void k_prep(const float* __restrict__ W2,
                                              unsigned short* __restrict__ W2b,
                                              const float* __restrict__ x,
                                              const float* __restrict__ ct,
                                              const float* __restrict__ W1,
                                              const float* __restrict__ b1,
                                              const float* __restrict__ b2,
                                              unsigned short* __restrict__ hbf,
                                              float* __restrict__ Qb) {
    const int t = threadIdx.x;
    const int bid = blockIdx.x;
    if (bid < 2048) {
        int i = bid * 256 + t;
        const f32x4* in = reinterpret_cast<const f32x4*>(W2);
        f32x4 v0 = in[2 * i], v1 = in[2 * i + 1];
        u32x4 o;
        o[0] = pk_bf2(v0[0], v0[1]);
        o[1] = pk_bf2(v0[2], v0[3]);
        o[2] = pk_bf2(v1[0], v1[1]);
        o[3] = pk_bf2(v1[2], v1[3]);
        reinterpret_cast<u32x4*>(W2b)[i] = o;
        return;
    }
    __shared__ unsigned short AB[128 * 128];   // 32KB: ct_bf then x_bf, swizzled
    __shared__ unsigned short WB[64 * 128];    // 16KB: W1b / b2b chunk, swizzled
    const int m0 = (bid - 2048) * 128;
    const int w = t >> 6, l = t & 63;
    const int lr = l & 15, g = l >> 4;

    #pragma unroll
    for (int it = 0; it < 8; ++it) {
        int r = (t >> 4) + it * 16;
        int gg = t & 15;
        int m = m0 + r;
        f32x4 a = (f32x4)(0.0f), b = (f32x4)(0.0f);
        if (m < M_TOK) {
            a = *reinterpret_cast<const f32x4*>(&ct[(size_t)m * DM + gg * 8]);
            b = *reinterpret_cast<const f32x4*>(&ct[(size_t)m * DM + gg * 8 + 4]);
        }
        u32x4 pk;
        pk[0] = pk_bf2(a[0], a[1]); pk[1] = pk_bf2(a[2], a[3]);
        pk[2] = pk_bf2(b[0], b[1]); pk[3] = pk_bf2(b[2], b[3]);
        *reinterpret_cast<u32x4*>(&AB[r * 128 + ((gg ^ (r & 7)) * 8)]) = pk;
    }

    for (int jc = 0; jc < 4; ++jc) {
        __syncthreads();
        #pragma unroll
        for (int it = 0; it < 4; ++it) {
            int r = (t >> 4) + it * 16;
            int gg = t & 15;
            const float* src = &W1[(size_t)(jc * 64 + r) * DM + gg * 8];
            f32x4 a = *reinterpret_cast<const f32x4*>(src);
            f32x4 b = *reinterpret_cast<const f32x4*>(src + 4);
            u32x4 pk;
            pk[0] = pk_bf2(a[0], a[1]); pk[1] = pk_bf2(a[2], a[3]);
            pk[2] = pk_bf2(b[0], b[1]); pk[3] = pk_bf2(b[2], b[3]);
            *reinterpret_cast<u32x4*>(&WB[r * 128 + ((gg ^ (r & 7)) * 8)]) = pk;
        }
        __syncthreads();
        f32x4 acc[2][4];
        #pragma unroll
        for (int a2 = 0; a2 < 2; ++a2)
            #pragma unroll
            for (int jf = 0; jf < 4; ++jf) acc[a2][jf] = (f32x4)(0.0f);
        #pragma unroll
        for (int ks = 0; ks < 4; ++ks) {
            bf16x8 A2[2], B4[4];
            #pragma unroll
            for (int tf = 0; tf < 2; ++tf) {
                int row = (2 * w + tf) * 16 + lr;
                A2[tf] = *reinterpret_cast<const bf16x8*>(
                    &AB[row * 128 + (((ks * 4 + g) ^ (row & 7)) * 8)]);
            }
            #pragma unroll
            for (int jf = 0; jf < 4; ++jf) {
                int row = jf * 16 + lr;
                B4[jf] = *reinterpret_cast<const bf16x8*>(
                    &WB[row * 128 + (((ks * 4 + g) ^ (row & 7)) * 8)]);
            }
            #pragma unroll
            for (int tf = 0; tf < 2; ++tf)
                #pragma unroll
                for (int jf = 0; jf < 4; ++jf)
                    acc[tf][jf] = __builtin_amdgcn_mfma_f32_16x16x32_bf16(
                        A2[tf], B4[jf], acc[tf][jf], 0, 0, 0);
        }
        #pragma unroll
        for (int jf = 0; jf < 4; ++jf) {
            int j = jc * 64 + jf * 16 + lr;
            float bv = b1[j];
            #pragma unroll
            for (int tf = 0; tf < 2; ++tf)
                #pragma unroll
                for (int rr = 0; rr < 4; ++rr) {
                    int m = m0 + (2 * w + tf) * 16 + g * 4 + rr;
                    if (m < M_TOK) {
                        float hv = fmaxf(acc[tf][jf][rr] + bv, 0.0f);
                        __hip_bfloat16 hb = __float2bfloat16(hv);
                        hbf[(size_t)m * DHID + j] = *reinterpret_cast<unsigned short*>(&hb);
                    }
                }
        }
    }

    __syncthreads();
    #pragma unroll
    for (int it = 0; it < 8; ++it) {
        int r = (t >> 4) + it * 16;
        int gg = t & 15;
        int m = m0 + r;
        f32x4 a = (f32x4)(0.0f), b = (f32x4)(0.0f);
        if (m < M_TOK) {
            a = *reinterpret_cast<const f32x4*>(&x[(size_t)m * DM + gg * 8]);
            b = *reinterpret_cast<const f32x4*>(&x[(size_t)m * DM + gg * 8 + 4]);
        }
        u32x4 pk;
        pk[0] = pk_bf2(a[0], a[1]); pk[1] = pk_bf2(a[2], a[3]);
        pk[2] = pk_bf2(b[0], b[1]); pk[3] = pk_bf2(b[2], b[3]);
        *reinterpret_cast<u32x4*>(&AB[r * 128 + ((gg ^ (r & 7)) * 8)]) = pk;
    }
    for (int oc = 0; oc < 2; ++oc) {
        #pragma unroll
        for (int it = 0; it < 4; ++it) {
            int r = (t >> 4) + it * 16;
            int gg = t & 15;
            const float* src = &b2[(size_t)(oc * 64 + r) * DM + gg * 8];
            f32x4 a = *reinterpret_cast<const f32x4*>(src);
            f32x4 b = *reinterpret_cast<const f32x4*>(src + 4);
            u32x4 pk;
            pk[0] = pk_bf2(a[0], a[1]); pk[1] = pk_bf2(a[2], a[3]);
            pk[2] = pk_bf2(b[0], b[1]); pk[3] = pk_bf2(b[2], b[3]);
            *reinterpret_cast<u32x4*>(&WB[r * 128 + ((gg ^ (r & 7)) * 8)]) = pk;
        }
        __syncthreads();
        f32x4 acc[2][4];
        #pragma unroll
        for (int a2 = 0; a2 < 2; ++a2)
            #pragma unroll
            for (int of = 0; of < 4; ++of) acc[a2][of] = (f32x4)(0.0f);
        #pragma unroll
        for (int ks = 0; ks < 4; ++ks) {
            bf16x8 A2[2], B4[4];
            #pragma unroll
            for (int tf = 0; tf < 2; ++tf) {
                int row = (2 * w + tf) * 16 + lr;
                A2[tf] = *reinterpret_cast<const bf16x8*>(
                    &AB[row * 128 + (((ks * 4 + g) ^ (row & 7)) * 8)]);
            }
            #pragma unroll
            for (int of = 0; of < 4; ++of) {
                int row = of * 16 + lr;
                B4[of] = *reinterpret_cast<const bf16x8*>(
                    &WB[row * 128 + (((ks * 4 + g) ^ (row & 7)) * 8)]);
            }
            #pragma unroll
            for (int tf = 0; tf < 2; ++tf)
                #pragma unroll
                for (int of = 0; of < 4; ++of)
                    acc[tf][of] = __builtin_amdgcn_mfma_f32_16x16x32_bf16(
                        A2[tf], B4[of], acc[tf][of], 0, 0, 0);
        }
        #pragma unroll
        for (int of = 0; of < 4; ++of) {
            int o = oc * 64 + of * 16 + lr;
            #pragma unroll
            for (int tf = 0; tf < 2; ++tf)
                #pragma unroll
                for (int rr = 0; rr < 4; ++rr) {
                    int m = m0 + (2 * w + tf) * 16 + g * 4 + rr;
                    if (m < M_TOK) Qb[(size_t)m * DM + o] = acc[tf][of][rr];
                }
        }
        __syncthreads();
    }
}

// ---------------- G-form GEMM v2: 256od x 128m blocks, 2x2 wave grid ----------------
// G[od,m] = sum_j W2b[od,j]*hbf[m,j]; QpT[o][m] = sum_d xin[m,d]*G[o*128+d,m].
// Block covers od in [ob2*256, +256) = o in {2*ob2, 2*ob2+1}; wave(wo,wm) owns
// 128od (= one full o, all 128 d in-wave) x 64m -> acc[8][4], 32 MFMA/wave/step.
// BK=32, 8 steps, dbuf LDS (A 16K + B 8K per buf), r2-proven XOR swizzle.
// bid&63 = ob2 -> XCD = ob2%8 -> per-XCD W2b slice 1MB, L2-resident.
__global__ __launch_bounds__(256, 2) void k_gemm(const unsigned short* __restrict__ W2b,
                                                 const unsigned short* __restrict__ hbf,
                                                 const float* __restrict__ xin,
                                                 float* __restrict__ QpT) {
    __shared__ unsigned short As[2][8192];   // [256 rows][32 j], 16KB each
    __shared__ unsigned short Bs[2][4096];   // [128 rows][32 j],  8KB each
    const int t = threadIdx.x;
    const int ob2 = blockIdx.x & 63;
    const int mb  = blockIdx.x >> 6;         // 0..77
    const int od0 = ob2 * 256;
    const int m0  = mb * 128;
    const int w = t >> 6, l = t & 63;
    const int wo = w >> 1, wm = w & 1;
    const int lr = l & 15, g = l >> 4;

    // staging: thread covers A rows sr+i*64 (i<4), B rows sr+i*64 (i<2); chunk sc
    const int sr  = t >> 2;
    const int sc  = t & 3;
    const int swz = (sc ^ ((sr >> 1) & 3)) * 8;
    const int wOf = sr * 32 + swz;           // + i*2048
    const unsigned short* aG = W2b + (size_t)(od0 + sr) * 256 + sc * 8;
    const unsigned short* bG = hbf + (size_t)(m0 + sr) * 256 + sc * 8;

    // read offsets: row = (wo*128|wm*64) + f*16 + lr; chunk = g ^ ((lr>>1)&3)
    const int rswz = (g ^ ((lr >> 1) & 3)) * 8;
    const int aR = wo * 4096 + lr * 32 + rswz;   // + fo*512
    const int bR = wm * 2048 + lr * 32 + rswz;   // + fm*512

    f32x4 acc[8][4];
    #pragma unroll
    for (int fo = 0; fo < 8; ++fo)
        #pragma unroll
        for (int fm = 0; fm < 4; ++fm) acc[fo][fm] = (f32x4)(0.0f);

    // prologue: stage step 0 directly; prefetch step 1 into regs
    {
        #pragma unroll
        for (int i = 0; i < 4; ++i)
            *reinterpret_cast<u32x4*>(&As[0][wOf + i * 2048]) =
                *reinterpret_cast<const u32x4*>(aG + i * 16384);
        #pragma unroll
        for (int i = 0; i < 2; ++i)
            *reinterpret_cast<u32x4*>(&Bs[0][wOf + i * 2048]) =
                *reinterpret_cast<const u32x4*>(bG + i * 16384);
    }
    u32x4 nA0 = *reinterpret_cast<const u32x4*>(aG + 32);
    u32x4 nA1 = *reinterpret_cast<const u32x4*>(aG + 16384 + 32);
    u32x4 nA2 = *reinterpret_cast<const u32x4*>(aG + 32768 + 32);
    u32x4 nA3 = *reinterpret_cast<const u32x4*>(aG + 49152 + 32);
    u32x4 nB0 = *reinterpret_cast<const u32x4*>(bG + 32);
    u32x4 nB1 = *reinterpret_cast<const u32x4*>(bG + 16384 + 32);
    __syncthreads();

    int cur = 0;
    #pragma unroll
    for (int s = 0; s < 8; ++s) {
        bf16x8 bf0 = *reinterpret_cast<const bf16x8*>(&Bs[cur][bR]);
        bf16x8 bf1 = *reinterpret_cast<const bf16x8*>(&Bs[cur][bR + 512]);
        bf16x8 bf2 = *reinterpret_cast<const bf16x8*>(&Bs[cur][bR + 1024]);
        bf16x8 bf3 = *reinterpret_cast<const bf16x8*>(&Bs[cur][bR + 1536]);
        if (s < 7) {   // write prefetched step s+1 into the other buffer
            *reinterpret_cast<u32x4*>(&As[cur ^ 1][wOf])        = nA0;
            *reinterpret_cast<u32x4*>(&As[cur ^ 1][wOf + 2048]) = nA1;
            *reinterpret_cast<u32x4*>(&As[cur ^ 1][wOf + 4096]) = nA2;
            *reinterpret_cast<u32x4*>(&As[cur ^ 1][wOf + 6144]) = nA3;
            *reinterpret_cast<u32x4*>(&Bs[cur ^ 1][wOf])        = nB0;
            *reinterpret_cast<u32x4*>(&Bs[cur ^ 1][wOf + 2048]) = nB1;
        }
        if (s < 6) {   // prefetch step s+2 from global
            nA0 = *reinterpret_cast<const u32x4*>(aG + (s + 2) * 32);
            nA1 = *reinterpret_cast<const u32x4*>(aG + 16384 + (s + 2) * 32);
            nA2 = *reinterpret_cast<const u32x4*>(aG + 32768 + (s + 2) * 32);
            nA3 = *reinterpret_cast<const u32x4*>(aG + 49152 + (s + 2) * 32);
            nB0 = *reinterpret_cast<const u32x4*>(bG + (s + 2) * 32);
            nB1 = *reinterpret_cast<const u32x4*>(bG + 16384 + (s + 2) * 32);
        }
        __builtin_amdgcn_s_setprio(1);
        #pragma unroll
        for (int fo = 0; fo < 8; ++fo) {
            bf16x8 af = *reinterpret_cast<const bf16x8*>(&As[cur][aR + fo * 512]);
            acc[fo][0] = __builtin_amdgcn_mfma_f32_16x16x32_bf16(af, bf0, acc[fo][0], 0, 0, 0);
            acc[fo][1] = __builtin_amdgcn_mfma_f32_16x16x32_bf16(af, bf1, acc[fo][1], 0, 0, 0);
            acc[fo][2] = __builtin_amdgcn_mfma_f32_16x16x32_bf16(af, bf2, acc[fo][2], 0, 0, 0);
            acc[fo][3] = __builtin_amdgcn_mfma_f32_16x16x32_bf16(af, bf3, acc[fo][3], 0, 0, 0);
        }
        __builtin_amdgcn_s_setprio(0);
        __syncthreads();
        cur ^= 1;
    }

    // epilogue: acc[fo][fm][r] = G[od0 + wo*128 + fo*16 + g*4 + r][m0 + wm*64 + fm*16 + lr]
    // wave's od-range is one full o = 2*ob2 + wo; d = fo*16 + g*4 + r (in-wave complete)
    const int o = ob2 * 2 + wo;
    #pragma unroll
    for (int fm = 0; fm < 4; ++fm) {
        int m = m0 + wm * 64 + fm * 16 + lr;
        int mx = m < M_TOK ? m : (M_TOK - 1);
        const f32x4* xr = reinterpret_cast<const f32x4*>(&xin[(size_t)mx * DM]);
        float q = 0.0f;
        #pragma unroll
        for (int fo = 0; fo < 8; ++fo) {
            f32x4 xv = xr[fo * 4 + g];
            q += xv[0] * acc[fo][fm][0] + xv[1] * acc[fo][fm][1]
               + xv[2] * acc[fo][fm][2] + xv[3] * acc[fo][fm][3];
        }
        q += __shfl_xor(q, 16, 64);
        q += __shfl_xor(q, 32, 64);
        if (l < 16 && m < M_TOK) QpT[(size_t)o * MPH + m] = q;
    }
}

// ---------------- attention + W_out(global-stream) + residual + layernorm ----------------
// (unchanged from round 10 — verified)
__global__ __launch_bounds__(256) void k_attn(const float* __restrict__ QpT,
                                              const float* __restrict__ Qb,
                                              const float* __restrict__ Kenc,
                                              const float* __restrict__ Venc,
                                              const float* __restrict__ xin,
                                              const float* __restrict__ Wout,
                                              const float* __restrict__ gamma,
                                              const float* __restrict__ beta,
                                              float* __restrict__ out) {
    __shared__ float Qs[12][132];
    __shared__ float Ks[12][132];
    __shared__ float Vs[12][132];
    __shared__ float Ss[12][12][8];
    __shared__ float Os[12][132];
    const int t = threadIdx.x;
    const int b = blockIdx.x / NN_;
    const int n = blockIdx.x % NN_;

    for (int e = t; e < 1536; e += 256) {
        int row = e >> 7, o = e & 127;
        size_t mrow = (size_t)(b * NP + row) * NN_ + n;
        Qs[row][o] = Qb[mrow * DM + o] + QpT[(size_t)o * MPH + mrow];
    }
    for (int e = t; e < 384; e += 256) {
        int row = e >> 5, c4 = e & 31;
        size_t mrow = (size_t)(b * NP + row) * NN_ + n;
        *reinterpret_cast<f32x4*>(&Ks[row][c4 * 4]) =
            *reinterpret_cast<const f32x4*>(&Kenc[mrow * DM + c4 * 4]);
        *reinterpret_cast<f32x4*>(&Vs[row][c4 * 4]) =
            *reinterpret_cast<const f32x4*>(&Venc[mrow * DM + c4 * 4]);
    }
    __syncthreads();
    if (t < 144) {
        int q = t / 12, p = t % 12;
        #pragma unroll
        for (int hh = 0; hh < 8; ++hh) {
            const f32x4* qv = reinterpret_cast<const f32x4*>(&Qs[q][hh * 16]);
            const f32x4* kv = reinterpret_cast<const f32x4*>(&Ks[p][hh * 16]);
            float s = 0.0f;
            #pragma unroll
            for (int c = 0; c < 4; ++c) {
                f32x4 a = qv[c], bb = kv[c];
                s += a[0] * bb[0] + a[1] * bb[1] + a[2] * bb[2] + a[3] * bb[3];
            }
            Ss[q][p][hh] = s * 0.25f;
        }
    }
    __syncthreads();
    if (t < 96) {
        int q = t >> 3, hh = t & 7;
        float mx = -1e30f;
        #pragma unroll
        for (int p = 0; p < 12; ++p) mx = fmaxf(mx, Ss[q][p][hh]);
        float ev[12]; float sum = 0.0f;
        #pragma unroll
        for (int p = 0; p < 12; ++p) { ev[p] = __expf(Ss[q][p][hh] - mx); sum += ev[p]; }
        float inv = 1.0f / sum;
        #pragma unroll
        for (int p = 0; p < 12; ++p) Ss[q][p][hh] = ev[p] * inv;
    }
    __syncthreads();
    #pragma unroll
    for (int i = 0; i < 6; ++i) {
        int e = i * 256 + t;
        int q = e >> 7, hk = e & 127, hh = hk >> 4;
        float acc = 0.0f;
        #pragma unroll
        for (int p = 0; p < 12; ++p) acc += Ss[q][p][hh] * Vs[p][hk];
        Os[q][hk] = acc;
    }
    __syncthreads();
    {
        const int o  = t & 127;
        const int qh = (t >> 7) * 6;
        const f32x4* wrow = reinterpret_cast<const f32x4*>(&Wout[(size_t)o * DM]);
        float pacc[6] = {0, 0, 0, 0, 0, 0};
        for (int c = 0; c < 32; ++c) {
            f32x4 wv = wrow[c];
            #pragma unroll
            for (int qq = 0; qq < 6; ++qq) {
                f32x4 ov = *reinterpret_cast<const f32x4*>(&Os[qh + qq][c * 4]);
                pacc[qq] += wv[0] * ov[0] + wv[1] * ov[1] + wv[2] * ov[2] + wv[3] * ov[3];
            }
        }
        #pragma unroll
        for (int qq = 0; qq < 6; ++qq) {
            size_t mrow = (size_t)(b * NP + qh + qq) * NN_ + n;
            Qs[qh + qq][o] = pacc[qq] + xin[mrow * DM + o];
        }
    }
    __syncthreads();
    const int wv_ = t >> 6, ll = t & 63;
    for (int rq = wv_; rq < 12; rq += 4) {
        float v0 = Qs[rq][ll], v1 = Qs[rq][ll + 64];
        float s = v0 + v1, ss = v0 * v0 + v1 * v1;
        #pragma unroll
        for (int msk = 1; msk < 64; msk <<= 1) {
            s += __shfl_xor(s, msk, 64);
            ss += __shfl_xor(ss, msk, 64);
        }
        float mu = s * (1.0f / 128.0f);
        float var = ss * (1.0f / 128.0f) - mu * mu;
        float rs = rsqrtf(var + 1e-5f);
        size_t mrow = (size_t)(b * NP + rq) * NN_ + n;
        out[mrow * DM + ll]      = (v0 - mu) * rs * gamma[ll] + beta[ll];
        out[mrow * DM + ll + 64] = (v1 - mu) * rs * gamma[ll + 64] + beta[ll + 64];
    }
}

// ---------------- launcher ----------------
extern "C" void kernel_launch(void* const* d_in, const int* in_sizes, int n_in,
                              void* d_out, int out_size, void* d_ws, size_t ws_size,
                              hipStream_t stream) {
    const float* xin   = (const float*)d_in[0];
    const float* Kenc  = (const float*)d_in[1];
    const float* Venc  = (const float*)d_in[2];
    const float* ct    = (const float*)d_in[3];
    const float* W1    = (const float*)d_in[4];
    const float* b1    = (const float*)d_in[5];
    const float* W2    = (const float*)d_in[6];
    const float* b2    = (const float*)d_in[7];
    const float* Wout  = (const float*)d_in[8];
    const float* gamma = (const float*)d_in[9];
    const float* beta  = (const float*)d_in[10];
    float* out = (float*)d_out;

    char* ws = (char*)d_ws;
    unsigned short* W2b = (unsigned short*)(ws);              //  8,388,608 B  [16384][256] bf16
    unsigned short* hbf = (unsigned short*)(ws + 8388608);    //  5,111,808 B  [9984][256] bf16
    float* Qb  = (float*)(ws + 13500416);                     //  5,087,232 B  [9936][128] f32
    float* QpT = (float*)(ws + 18587648);                     //  5,111,808 B  [128][9984] f32

    // zero the hbf pad rows (9936..9983) so the GEMM's B-tail is clean
    hipMemsetAsync(ws + 8388608 + (size_t)M_TOK * DHID * 2, 0,
                   (size_t)(MPH - M_TOK) * DHID * 2, stream);
    hipLaunchKernelGGL(k_prep, dim3(2126), dim3(256), 0, stream,
                       W2, W2b, xin, ct, W1, b1, b2, hbf, Qb);
    hipLaunchKernelGGL(k_gemm, dim3(78 * 64), dim3(256), 0, stream, W2b, hbf, xin, QpT);
    hipLaunchKernelGGL(k_attn, dim3(828), dim3(256), 0, stream, QpT, Qb, Kenc, Venc,
                       xin, Wout, gamma, beta, out);
}